// Round 14
// baseline (549.908 us; speedup 1.0000x reference)
//
#include <hip/hip_runtime.h>
#include <hip/hip_bf16.h>

// Problem dims
#define NTOK 4096   // B*N
#define DDIM 768
#define NEA  24
#define NHEAD 12
#define HDIM 64
#define NEF  8
#define HSD  1536
#define SEQL 1024
#define NB   4
#define MAXTILE 104   // <= 72 routed row-tiles + 32 shared row-tiles
#define NQKV 1664     // 1536 q cols + 128 kv cols (fused)

using bf16 = __hip_bfloat16;

typedef float v4f __attribute__((ext_vector_type(4)));
typedef short v8s __attribute__((ext_vector_type(8)));
typedef __bf16 v8bf __attribute__((ext_vector_type(8)));

typedef __attribute__((address_space(3))) unsigned lds_u32_t;
typedef const __attribute__((address_space(1))) unsigned glb_u32_t;

__device__ __forceinline__ void gload16(const void* g, void* l) {
  __builtin_amdgcn_global_load_lds((glb_u32_t*)g, (lds_u32_t*)l, 16, 0, 0);
}

__device__ __forceinline__ float gelu_f(float x) {
  return 0.5f * x * (1.0f + erff(x * 0.70710678118654752440f));
}

__device__ __forceinline__ short f2bf_s(float x) {
  bf16 h = __float2bfloat16(x);
  return __builtin_bit_cast(short, h);
}

// bijective XCD swizzle (nwg % 8 == 0): contiguous chunk per XCD -> L2 reuse
__device__ __forceinline__ int xcd_swz(int lin, int nwg) {
  return (lin & 7) * (nwg >> 3) + (lin >> 3);
}

// ---------------- MFMA GEMM core: 128x128 tile, BK=32 ----------------
// 2-buffer pipeline: stage tile s+1 while computing tile s (R5-verified).
__device__ __forceinline__ void gemm_core(const short* gA0, const short* gA1,
                                          const short* gB0, const short* gB1,
                                          short* lA, short* lB, int steps,
                                          v4f (&acc)[4][4])
{
  const int tid = threadIdx.x;
  const int w = tid >> 6, l = tid & 63;
  const int wr = (w >> 1) * 64, wc = (w & 1) * 64;
  const int fr = l & 15, ko = (l >> 4) * 8;
  const int sb = w * 1024;              // wave staging base (shorts)
  gload16(gA0, lA + sb); gload16(gA1, lA + sb + 512);
  gload16(gB0, lB + sb); gload16(gB1, lB + sb + 512);
  gA0 += 32; gA1 += 32; gB0 += 32; gB1 += 32;
  __syncthreads();                      // drains vmcnt(0): tile 0 visible
  int cur = 0;
  for (int s = 0; s < steps; ++s) {
    const int nxt = cur ^ 1;
    if (s + 1 < steps) {                // issue next tile EARLY (overlaps MFMA)
      gload16(gA0, lA + nxt * 4096 + sb);
      gload16(gA1, lA + nxt * 4096 + sb + 512);
      gload16(gB0, lB + nxt * 4096 + sb);
      gload16(gB1, lB + nxt * 4096 + sb + 512);
      gA0 += 32; gA1 += 32; gB0 += 32; gB1 += 32;
    }
    const short* bA = lA + cur * 4096;
    const short* bB = lB + cur * 4096;
    v8s av[4], bv[4];
#pragma unroll
    for (int mi = 0; mi < 4; ++mi)
      av[mi] = *(const v8s*)(bA + (wr + mi * 16 + fr) * 32 + ko);
#pragma unroll
    for (int ni = 0; ni < 4; ++ni)
      bv[ni] = *(const v8s*)(bB + (wc + ni * 16 + fr) * 32 + ko);
#pragma unroll
    for (int mi = 0; mi < 4; ++mi)
#pragma unroll
      for (int ni = 0; ni < 4; ++ni)
        acc[mi][ni] = __builtin_amdgcn_mfma_f32_16x16x32_bf16(
            __builtin_bit_cast(v8bf, av[mi]), __builtin_bit_cast(v8bf, bv[ni]),
            acc[mi][ni], 0, 0, 0);
    __syncthreads();
    cur = nxt;
  }
}

// dense GEMM: EPI 0 = f32, 3 = bf16 out, 4 = split-K atomicAdd f32.
// EPI 4 uses gridDim.z K-slices (pre-fill C with the residual before launch).
template<int EPI>
__global__ __launch_bounds__(256, 4) void k_gemm(const short* __restrict__ A,
    const short* __restrict__ Bt, float* __restrict__ C, bf16* __restrict__ Cb,
    int N, int K)
{
  const int nwg = gridDim.x * gridDim.y;
  const int swz = xcd_swz(blockIdx.x + gridDim.x * blockIdx.y, nwg);
  const int m0 = (swz % gridDim.x) * 128, n0 = (swz / gridDim.x) * 128;
  const int kspl = (EPI == 4) ? (K / (int)gridDim.z) : K;
  const int kbase = (EPI == 4) ? (int)blockIdx.z * kspl : 0;
  __shared__ __align__(16) short lA[2 * 128 * 32];
  __shared__ __align__(16) short lB[2 * 128 * 32];
  const int tid = threadIdx.x, w = tid >> 6, l = tid & 63;
  const int ca = w * 128 + l, cb = ca + 64;
  const short* gA0 = A + (size_t)(m0 + (ca >> 2)) * K + (ca & 3) * 8 + kbase;
  const short* gA1 = A + (size_t)(m0 + (cb >> 2)) * K + (cb & 3) * 8 + kbase;
  const short* gB0 = Bt + (size_t)(n0 + (ca >> 2)) * K + (ca & 3) * 8 + kbase;
  const short* gB1 = Bt + (size_t)(n0 + (cb >> 2)) * K + (cb & 3) * 8 + kbase;
  v4f acc[4][4];
  v4f z = {0.f, 0.f, 0.f, 0.f};
#pragma unroll
  for (int i = 0; i < 4; ++i)
#pragma unroll
    for (int j = 0; j < 4; ++j) acc[i][j] = z;
  gemm_core(gA0, gA1, gB0, gB1, lA, lB, kspl >> 5, acc);
  const int wr = (w >> 1) * 64, wc = (w & 1) * 64;
  const int fr = l & 15, rq = (l >> 4) * 4;
#pragma unroll
  for (int mi = 0; mi < 4; ++mi)
#pragma unroll
    for (int ni = 0; ni < 4; ++ni)
#pragma unroll
      for (int j = 0; j < 4; ++j) {
        int rg = m0 + wr + mi * 16 + rq + j;
        int cg = n0 + wc + ni * 16 + fr;
        float v = acc[mi][ni][j];
        if (EPI == 3)      Cb[(size_t)rg * N + cg] = __float2bfloat16(v);
        else if (EPI == 4) atomicAdd(&C[(size_t)rg * N + cg], v);
        else               C[(size_t)rg * N + cg] = v;
      }
}

// grouped MoE GEMM over a COMPACT tile table (tmeta[i] = (e<<20)|row0).
// PHASE 0: mid = gelu(h2[token] @ W1 + b1) -> bf16
// PHASE 1: yacc[token] += w[slot] * (hmid[slot] @ W2) via f32 atomicAdd
//          (2 routed + 1 shared contribution per element; commutative adds)
template<int PHASE>
__global__ __launch_bounds__(256, 5) void k_gemm_moe(
    const short* __restrict__ Aact, const short* __restrict__ Wt,
    const short* __restrict__ Wst, const float* __restrict__ b1f,
    const float* __restrict__ bs1, const float* __restrict__ wsl,
    const int* __restrict__ off, const int* __restrict__ cnt,
    const int* __restrict__ list, const int* __restrict__ tmeta,
    const int* __restrict__ ntl, short* __restrict__ outb,
    float* __restrict__ outf)
{
  constexpr int K = (PHASE == 0) ? DDIM : HSD;
  constexpr int N = (PHASE == 0) ? HSD : DDIM;
  const int nwg = gridDim.x * gridDim.y;
  const int swz = xcd_swz(blockIdx.x + gridDim.x * blockIdx.y, nwg);
  const int ti = swz % gridDim.x;
  const int n0 = (swz / gridDim.x) * 128;
  if (ti >= ntl[0]) return;
  const int mm = tmeta[ti];
  const int e = mm >> 20;
  const int r0 = mm & 0xFFFFF;
  const int base = (e < 8) ? off[e] : NTOK * 2;
  const int c    = (e < 8) ? cnt[e] : NTOK;
  const int rows = c - r0;
  const short* Bt = (e < 8) ? Wt + (size_t)e * N * K : Wst;
  __shared__ __align__(16) short lA[2 * 128 * 32];
  __shared__ __align__(16) short lB[2 * 128 * 32];
  const int tid = threadIdx.x, w = tid >> 6, l = tid & 63;
  const int ca = w * 128 + l, cb = ca + 64;

  auto arowptr = [&](int chunk) -> const short* {
    int r = chunk >> 2;
    int re = (r < rows) ? r : (rows - 1);
    int slot = base + r0 + re;
    if (PHASE == 0) {
      int tok = (e < 8) ? list[slot] : (slot - NTOK * 2);
      return Aact + (size_t)tok * DDIM;
    } else {
      return Aact + (size_t)slot * HSD;
    }
  };
  const short* gA0 = arowptr(ca) + (ca & 3) * 8;
  const short* gA1 = arowptr(cb) + (cb & 3) * 8;
  const short* gB0 = Bt + (size_t)(n0 + (ca >> 2)) * K + (ca & 3) * 8;
  const short* gB1 = Bt + (size_t)(n0 + (cb >> 2)) * K + (cb & 3) * 8;
  v4f acc[4][4];
  v4f z = {0.f, 0.f, 0.f, 0.f};
#pragma unroll
  for (int i = 0; i < 4; ++i)
#pragma unroll
    for (int j = 0; j < 4; ++j) acc[i][j] = z;
  gemm_core(gA0, gA1, gB0, gB1, lA, lB, K >> 5, acc);
  const int wr = (w >> 1) * 64, wc = (w & 1) * 64;
  const int fr = l & 15, rq = (l >> 4) * 4;
  const float* bias = (PHASE == 0) ? ((e < 8) ? b1f + e * HSD : bs1) : nullptr;
#pragma unroll
  for (int mi = 0; mi < 4; ++mi)
#pragma unroll
    for (int ni = 0; ni < 4; ++ni)
#pragma unroll
      for (int j = 0; j < 4; ++j) {
        int rl = wr + mi * 16 + rq + j;
        if (rl >= rows) continue;
        int slot = base + r0 + rl;
        int cg = n0 + wc + ni * 16 + fr;
        float v = acc[mi][ni][j];
        if (PHASE == 0) {
          v = gelu_f(v + bias[cg]);
          outb[(size_t)slot * HSD + cg] = f2bf_s(v);
        } else {
          int tok = (e < 8) ? list[slot] : (slot - NTOK * 2);
          atomicAdd(&outf[(size_t)tok * DDIM + cg], v * wsl[slot]);
        }
      }
}

// ------- FUSED LayerNorm + routing A: one wave per token, LN in regs -------
__global__ __launch_bounds__(256) void k_lnrouteA(const float* __restrict__ x,
    const float* __restrict__ lg_, const float* __restrict__ lb_,
    const float* __restrict__ gt, bf16* __restrict__ hb,
    int* __restrict__ topi, float* __restrict__ topv)
{
  const int t = blockIdx.x * 4 + (threadIdx.x >> 6);
  const int l = threadIdx.x & 63;
  const float* xr = x + (size_t)t * DDIM;
  float v[12];
  float s = 0.f, q = 0.f;
#pragma unroll
  for (int m = 0; m < 12; ++m) {
    v[m] = xr[l + 64 * m];
    s += v[m]; q += v[m] * v[m];
  }
#pragma unroll
  for (int m = 32; m >= 1; m >>= 1) { s += __shfl_xor(s, m); q += __shfl_xor(q, m); }
  const float mean = s * (1.f / DDIM);
  const float inv = rsqrtf(q * (1.f / DDIM) - mean * mean + 1e-5f);
  float hr[12];
#pragma unroll
  for (int m = 0; m < 12; ++m) {
    int d = l + 64 * m;
    hr[m] = (v[m] - mean) * inv * lg_[d] + lb_[d];
    hb[(size_t)t * DDIM + d] = __float2bfloat16(hr[m]);
  }
  float lg[NEA];
#pragma unroll
  for (int e = 0; e < NEA; ++e) {
    const float* ge = gt + e * DDIM;
    float a = 0.f;
#pragma unroll
    for (int m = 0; m < 12; ++m) a += hr[m] * ge[l + 64 * m];
#pragma unroll
    for (int m = 32; m >= 1; m >>= 1) a += __shfl_xor(a, m);
    lg[e] = a;
  }
  unsigned used = 0;
  int sel[NHEAD]; float bvk[NHEAD];
#pragma unroll
  for (int k = 0; k < NHEAD; ++k) {
    float bv = -3e30f; int best = 0;
#pragma unroll
    for (int e = 0; e < NEA; ++e)
      if (!((used >> e) & 1u) && lg[e] > bv) { bv = lg[e]; best = e; }
    used |= 1u << best; sel[k] = best; bvk[k] = bv;
  }
  const float mx = bvk[0];
  float pvk[NHEAD], ssum = 0.f;
#pragma unroll
  for (int k = 0; k < NHEAD; ++k) { pvk[k] = expf(bvk[k] - mx); ssum += pvk[k]; }
  const float invs = 1.f / ssum;
  if (l == 0) {
#pragma unroll
    for (int k = 0; k < NHEAD; ++k) {
      topi[t * NHEAD + k] = sel[k];
      topv[t * NHEAD + k] = pvk[k] * invs;
    }
  }
}

// ------- FUSED LayerNorm + routing F -------
__global__ __launch_bounds__(256) void k_lnrouteF(const float* __restrict__ x,
    const float* __restrict__ lg_, const float* __restrict__ lb_,
    const float* __restrict__ gt, bf16* __restrict__ hb,
    int* __restrict__ ef, float* __restrict__ wf, int* __restrict__ cnt)
{
  const int t = blockIdx.x * 4 + (threadIdx.x >> 6);
  const int l = threadIdx.x & 63;
  const float* xr = x + (size_t)t * DDIM;
  float v[12];
  float s = 0.f, q = 0.f;
#pragma unroll
  for (int m = 0; m < 12; ++m) {
    v[m] = xr[l + 64 * m];
    s += v[m]; q += v[m] * v[m];
  }
#pragma unroll
  for (int m = 32; m >= 1; m >>= 1) { s += __shfl_xor(s, m); q += __shfl_xor(q, m); }
  const float mean = s * (1.f / DDIM);
  const float inv = rsqrtf(q * (1.f / DDIM) - mean * mean + 1e-5f);
  float hr[12];
#pragma unroll
  for (int m = 0; m < 12; ++m) {
    int d = l + 64 * m;
    hr[m] = (v[m] - mean) * inv * lg_[d] + lb_[d];
    hb[(size_t)t * DDIM + d] = __float2bfloat16(hr[m]);
  }
  float lg[NEF];
#pragma unroll
  for (int e = 0; e < NEF; ++e) {
    const float* ge = gt + e * DDIM;
    float a = 0.f;
#pragma unroll
    for (int m = 0; m < 12; ++m) a += hr[m] * ge[l + 64 * m];
#pragma unroll
    for (int m = 32; m >= 1; m >>= 1) a += __shfl_xor(a, m);
    lg[e] = a;
  }
  unsigned used = 0;
  int sel[2]; float bvk[2];
#pragma unroll
  for (int k = 0; k < 2; ++k) {
    float bv = -3e30f; int best = 0;
#pragma unroll
    for (int e = 0; e < NEF; ++e)
      if (!((used >> e) & 1u) && lg[e] > bv) { bv = lg[e]; best = e; }
    used |= 1u << best; sel[k] = best; bvk[k] = bv;
  }
  const float mx = bvk[0];
  float p0 = expf(bvk[0] - mx), p1 = expf(bvk[1] - mx);
  const float invs = 1.f / (p0 + p1);
  if (l == 0) {
    ef[t * 2 + 0] = sel[0]; wf[t * 2 + 0] = p0 * invs;
    ef[t * 2 + 1] = sel[1]; wf[t * 2 + 1] = p1 * invs;
    atomicAdd(&cnt[sel[0]], 1);
    atomicAdd(&cnt[sel[1]], 1);
  }
}

// gate transpose for current task: dst[e][d] = src[task][d][e]
__global__ void k_packGT(const float* __restrict__ src, const int* __restrict__ task,
                         float* __restrict__ dst, int E)
{
  int idx = blockIdx.x * 256 + threadIdx.x;
  if (idx >= E * DDIM) return;
  int e = idx / DDIM, d = idx - e * DDIM;
  dst[idx] = src[(size_t)task[0] * DDIM * E + (size_t)d * E + e];
}

// offsets + COMPACT 128-row tile table: tmeta[i] = (expert<<20)|row0
__global__ void k_off(const int* __restrict__ cnt, int* __restrict__ off,
                      int* __restrict__ cur, int* __restrict__ tmeta,
                      int* __restrict__ ntl)
{
  if (threadIdx.x == 0 && blockIdx.x == 0) {
    int a = 0;
    for (int e = 0; e < NEF; ++e) { off[e] = a; cur[e] = a; a += cnt[e]; }
    off[NEF] = a;
    int n = 0;
    for (int e = 0; e < NEF; ++e)
      for (int r = 0; r < cnt[e]; r += 128) tmeta[n++] = (e << 20) | r;
    for (int r = 0; r < NTOK; r += 128) tmeta[n++] = (8 << 20) | r;
    ntl[0] = n;
  }
}

__global__ void k_fill(const int* __restrict__ ef, const float* __restrict__ wf,
                       int* __restrict__ cur, int* __restrict__ list,
                       float* __restrict__ wsl)
{
  int t = blockIdx.x * 256 + threadIdx.x;
  if (t >= NTOK) return;
  for (int k = 0; k < 2; ++k) {
    int e = ef[t * 2 + k];
    int slot = atomicAdd(&cur[e], 1);
    list[slot] = t;
    wsl[slot] = wf[t * 2 + k];
  }
  list[NTOK * 2 + t] = t;
  wsl[NTOK * 2 + t] = 1.f;
}

// ---------------- attention helpers ----------------
// kv = hallqb cols 1536..1663 (+ b_kv bias) -> bf16 [4096][128]
__global__ void k_packKV(const bf16* __restrict__ hq, const float* __restrict__ bkv,
                         bf16* __restrict__ kvb)
{
  int idx = blockIdx.x * 256 + threadIdx.x;   // < 4096*128
  int t = idx >> 7, j = idx & 127;
  float v = __bfloat162float(hq[(size_t)t * NQKV + 1536 + j]) + bkv[j];
  kvb[idx] = __float2bfloat16(v);
}

// MFMA flash attention + FUSED weighted scatter into dense.
// grid (N/64, H, B), block 256 (4 waves). Q gathered from hallqb via topi.
__global__ __launch_bounds__(256, 2) void k_attn_mfma(const bf16* __restrict__ hq,
    const int* __restrict__ topi, const float* __restrict__ topv,
    const bf16* __restrict__ kv, bf16* __restrict__ dense)
{
  __shared__ __align__(16) short Qs[64 * 64];
  __shared__ __align__(16) short Ks[64 * 64];
  __shared__ __align__(16) short Vs[64 * 64];   // transposed: row=d, col=j
  __shared__ __align__(16) short Ps[64 * 64];
  const int i0 = blockIdx.x * 64;
  const int h = blockIdx.y;
  const int b = blockIdx.z;
  const int tid = threadIdx.x;
  const int w = tid >> 6, l = tid & 63;
  const int g = l >> 4, fq = l & 15;
  const short* qg = (const short*)hq;
  const short* kvg = (const short*)kv;

  // stage Q (gathered): chunks tid (rows 0..31) and tid+256 (rows 32..63)
  {
    int c0 = tid, c1 = tid + 256;
    int r0 = c0 >> 3, s0 = (c0 & 7) ^ (r0 & 7);
    int r1 = c1 >> 3, s1 = (c1 & 7) ^ (r1 & 7);
    int t0 = b * SEQL + i0 + r0, t1 = b * SEQL + i0 + r1;
    int e0 = topi[t0 * NHEAD + h], e1 = topi[t1 * NHEAD + h];
    gload16(qg + (size_t)t0 * NQKV + e0 * HDIM + s0 * 8, Qs + w * 512);
    gload16(qg + (size_t)t1 * NQKV + e1 * HDIM + s1 * 8, Qs + 2048 + w * 512);
  }

  float m_run[4], l_run[4];
  v4f oacc[4];
#pragma unroll
  for (int r = 0; r < 4; ++r) { m_run[r] = -1e30f; l_run[r] = 0.f; }
#pragma unroll
  for (int nd = 0; nd < 4; ++nd) oacc[nd] = (v4f){0.f, 0.f, 0.f, 0.f};

  const int vj = tid & 63;            // V staging: column j, wave covers d block
  const int vd0 = (tid >> 6) * 16;

  for (int jt = 0; jt < 16; ++jt) {
    if (jt) __syncthreads();          // previous tile's readers done
    // stage K
    {
      int c0 = tid, c1 = tid + 256;
      int r0 = c0 >> 3, s0 = (c0 & 7) ^ (r0 & 7);
      int r1 = c1 >> 3, s1 = (c1 & 7) ^ (r1 & 7);
      gload16(kvg + ((size_t)(b * SEQL + jt * 64 + r0)) * 128 + s0 * 8,
              Ks + w * 512);
      gload16(kvg + ((size_t)(b * SEQL + jt * 64 + r1)) * 128 + s1 * 8,
              Ks + 2048 + w * 512);
    }
    // stage V transposed (reg -> swizzled ds_write)
    {
      const short* gv = kvg + ((size_t)(b * SEQL + jt * 64 + vj)) * 128 + 64 + vd0;
      v8s a0 = *(const v8s*)gv;
      v8s a1 = *(const v8s*)(gv + 8);
#pragma unroll
      for (int k2 = 0; k2 < 8; ++k2) {
        int d = vd0 + k2;
        Vs[d * 64 + (((vj >> 3) ^ (d & 7)) << 3) + (vj & 7)] = a0[k2];
      }
#pragma unroll
      for (int k2 = 0; k2 < 8; ++k2) {
        int d = vd0 + 8 + k2;
        Vs[d * 64 + (((vj >> 3) ^ (d & 7)) << 3) + (vj & 7)] = a1[k2];
      }
    }
    __syncthreads();                  // staged data visible (incl. Q on jt=0)

    // QK^T: S[64q x 64j], this wave: q rows 16w..16w+15
    v8s aq[2];
#pragma unroll
    for (int kk = 0; kk < 2; ++kk)
      aq[kk] = *(const v8s*)&Qs[(16 * w + fq) * 64 + (((kk * 4 + g) ^ (fq & 7)) << 3)];
    v4f sacc[4];
#pragma unroll
    for (int n = 0; n < 4; ++n) {
      sacc[n] = (v4f){0.f, 0.f, 0.f, 0.f};
#pragma unroll
      for (int kk = 0; kk < 2; ++kk) {
        v8s bk = *(const v8s*)&Ks[(16 * n + fq) * 64 + (((kk * 4 + g) ^ (fq & 7)) << 3)];
        sacc[n] = __builtin_amdgcn_mfma_f32_16x16x32_bf16(
            __builtin_bit_cast(v8bf, aq[kk]), __builtin_bit_cast(v8bf, bk),
            sacc[n], 0, 0, 0);
      }
    }
#pragma unroll
    for (int n = 0; n < 4; ++n) sacc[n] *= 0.125f;   // HD^-0.5

    // online softmax; C layout: row = 4g+r (in wave strip), col = 16n+fq
#pragma unroll
    for (int r = 0; r < 4; ++r) {
      float mt = fmaxf(fmaxf(sacc[0][r], sacc[1][r]), fmaxf(sacc[2][r], sacc[3][r]));
      mt = fmaxf(mt, __shfl_xor(mt, 1));
      mt = fmaxf(mt, __shfl_xor(mt, 2));
      mt = fmaxf(mt, __shfl_xor(mt, 4));
      mt = fmaxf(mt, __shfl_xor(mt, 8));
      float mnew = fmaxf(m_run[r], mt);
      float corr = __expf(m_run[r] - mnew);
      float pv[4], ps = 0.f;
#pragma unroll
      for (int n = 0; n < 4; ++n) { pv[n] = __expf(sacc[n][r] - mnew); ps += pv[n]; }
      ps += __shfl_xor(ps, 1);
      ps += __shfl_xor(ps, 2);
      ps += __shfl_xor(ps, 4);
      ps += __shfl_xor(ps, 8);
      l_run[r] = l_run[r] * corr + ps;
      m_run[r] = mnew;
#pragma unroll
      for (int nd = 0; nd < 4; ++nd) oacc[nd][r] *= corr;
      int qrow = 16 * w + 4 * g + r;
#pragma unroll
      for (int n = 0; n < 4; ++n)
        Ps[qrow * 64 + (((2 * n + (fq >> 3)) ^ (qrow & 7)) << 3) + (fq & 7)] =
            f2bf_s(pv[n]);
    }
    // wave-private P: drain LDS writes before cross-lane reads (rule #18)
    asm volatile("s_waitcnt lgkmcnt(0)" ::: "memory");
    __builtin_amdgcn_sched_barrier(0);

    // PV: O[16q x 64d] += P[16q x 64j] @ V[64j x 64d] (Vs holds V^T)
#pragma unroll
    for (int kk = 0; kk < 2; ++kk) {
      v8s pa = *(const v8s*)&Ps[(16 * w + fq) * 64 + (((kk * 4 + g) ^ (fq & 7)) << 3)];
#pragma unroll
      for (int nd = 0; nd < 4; ++nd) {
        v8s vb = *(const v8s*)&Vs[(16 * nd + fq) * 64 + (((kk * 4 + g) ^ (fq & 7)) << 3)];
        oacc[nd] = __builtin_amdgcn_mfma_f32_16x16x32_bf16(
            __builtin_bit_cast(v8bf, pa), __builtin_bit_cast(v8bf, vb),
            oacc[nd], 0, 0, 0);
      }
    }
  }

  // fused epilogue: apply topv weight and scatter into dense (bf16)
#pragma unroll
  for (int r = 0; r < 4; ++r) {
    int t = b * SEQL + i0 + 16 * w + 4 * g + r;
    int e = topi[t * NHEAD + h];
    float sc = topv[t * NHEAD + h] / l_run[r];
#pragma unroll
    for (int nd = 0; nd < 4; ++nd)
      dense[(size_t)t * (NEA * HDIM) + e * HDIM + 16 * nd + fq] =
          __float2bfloat16(oacc[nd][r] * sc);
  }
}

// ---------------- weight packing (tiled transpose, coalesced both sides) ----
__global__ __launch_bounds__(256) void k_packT(const float* __restrict__ src,
                                               bf16* __restrict__ dst, int K, int N)
{
  __shared__ float tile[32][33];
  const size_t zoff = (size_t)blockIdx.z * K * N;
  const int k0 = blockIdx.x * 32, n0 = blockIdx.y * 32;
  const int tx = threadIdx.x & 31, ty = threadIdx.x >> 5;
#pragma unroll
  for (int i = 0; i < 32; i += 8)
    tile[ty + i][tx] = src[zoff + (size_t)(k0 + ty + i) * N + n0 + tx];
  __syncthreads();
#pragma unroll
  for (int i = 0; i < 32; i += 8)
    dst[zoff + (size_t)(n0 + ty + i) * K + k0 + tx] =
        __float2bfloat16(tile[tx][ty + i]);
}

// ---------------- final combine: out = x2 + b_out + yacc ----------------
__global__ void k_final(const float* __restrict__ x2, const float* __restrict__ bout,
                        const float* __restrict__ yacc, float* __restrict__ out)
{
  int idx = blockIdx.x * 256 + threadIdx.x;   // < 4096*768
  int d = idx % DDIM;
  out[idx] = x2[idx] + bout[d] + yacc[idx];
}

extern "C" void kernel_launch(void* const* d_in, const int* in_sizes, int n_in,
                              void* d_out, int out_size, void* d_ws, size_t ws_size,
                              hipStream_t stream) {
  const float* x      = (const float*)d_in[0];
  const int*   task   = (const int*)d_in[1];
  const float* ln1g   = (const float*)d_in[2];
  const float* ln1b   = (const float*)d_in[3];
  const float* ln2g   = (const float*)d_in[4];
  const float* ln2b   = (const float*)d_in[5];
  const float* gate_a = (const float*)d_in[6];
  const float* wq_in  = (const float*)d_in[7];
  const float* wq_out = (const float*)d_in[8];
  const float* w_kv   = (const float*)d_in[9];
  const float* b_kv   = (const float*)d_in[10];
  const float* gate_f = (const float*)d_in[11];
  const float* w1f    = (const float*)d_in[12];
  const float* b1f    = (const float*)d_in[13];
  const float* w2f    = (const float*)d_in[14];
  const float* b_out  = (const float*)d_in[15];
  const float* ws1    = (const float*)d_in[16];
  const float* bs1    = (const float*)d_in[17];
  const float* ws2    = (const float*)d_in[18];

  char* W = (char*)d_ws;
  size_t off_ = 0;
  auto alloc = [&](size_t b) { size_t o = off_; off_ += (b + 255) & ~(size_t)255; return o; };
  // region 1: h1b + hallqb live early; hmid (37.75 MB) reuses the region
  size_t o_reg1  = alloc(37748736);
  size_t o_h1b   = o_reg1;                   // [4096][768] bf16 (6.3 MB)
  size_t o_hallq = o_reg1 + 6291456;         // [4096][1664] bf16 (13.6 MB)
  size_t o_hmid  = o_reg1;                   // [12288][1536] bf16 (37.75 MB)
  // region 2
  size_t o_yacc  = alloc(12582912);          // [4096][768] f32 (FFN accumulator)
  size_t o_dense = alloc(12582912);
  size_t o_kvb   = alloc(1048576);
  size_t o_x2    = alloc(12582912);
  size_t o_h2b   = alloc(6291456);
  size_t o_btq   = alloc(2555904);           // [1664][768] bf16 (Wq_in^T ++ W_kv^T)
  size_t o_wqot  = alloc(2359296);
  size_t o_w1t   = alloc(18874368);
  size_t o_w2t   = alloc(18874368);
  size_t o_ws1t  = alloc(2359296);
  size_t o_ws2t  = alloc(2359296);
  size_t o_topi  = alloc(196608);
  size_t o_topv  = alloc(196608);
  size_t o_ef    = alloc(32768);
  size_t o_wf    = alloc(32768);
  size_t o_cnt   = alloc(1024);
  size_t o_offs  = alloc(1024);
  size_t o_cur   = alloc(1024);
  size_t o_list  = alloc(49152);
  size_t o_wsl   = alloc(49152);
  size_t o_tmeta = alloc(1024);
  size_t o_ntl   = alloc(256);
  size_t o_gta   = alloc(73728);
  size_t o_gtf   = alloc(24576);
  if (ws_size < off_) return;

  bf16*  h1b   = (bf16*)(W + o_h1b);
  bf16*  hallqb= (bf16*)(W + o_hallq);
  float* yacc  = (float*)(W + o_yacc);
  bf16*  dense = (bf16*)(W + o_dense);
  bf16*  kvbb  = (bf16*)(W + o_kvb);
  float* x2b   = (float*)(W + o_x2);
  bf16*  h2b   = (bf16*)(W + o_h2b);
  short* hmid  = (short*)(W + o_hmid);
  int*   topi  = (int*)(W + o_topi);
  float* topv  = (float*)(W + o_topv);
  int*   efp   = (int*)(W + o_ef);
  float* wfp   = (float*)(W + o_wf);
  int*   cntp  = (int*)(W + o_cnt);
  int*   offp  = (int*)(W + o_offs);
  int*   curp  = (int*)(W + o_cur);
  int*   listp = (int*)(W + o_list);
  float* wslp  = (float*)(W + o_wsl);
  int*   tmeta = (int*)(W + o_tmeta);
  int*   ntl   = (int*)(W + o_ntl);
  float* gta   = (float*)(W + o_gta);
  float* gtf   = (float*)(W + o_gtf);

  // 1) pack weights to bf16, transposed (N x K); gates to f32 transposed.
  k_packT<<<dim3(24, 2, 24), 256, 0, stream>>>(wq_in, (bf16*)(W + o_btq), 768, 64);
  k_packT<<<dim3(24, 4, 1), 256, 0, stream>>>(w_kv, (bf16*)(W + o_btq) + 1536 * 768, 768, 128);
  k_packT<<<dim3(48, 24, 1), 256, 0, stream>>>(wq_out, (bf16*)(W + o_wqot), 1536, 768);
  k_packT<<<dim3(24, 48, 8), 256, 0, stream>>>(w1f, (bf16*)(W + o_w1t), 768, 1536);
  k_packT<<<dim3(48, 24, 8), 256, 0, stream>>>(w2f, (bf16*)(W + o_w2t), 1536, 768);
  k_packT<<<dim3(24, 48, 1), 256, 0, stream>>>(ws1, (bf16*)(W + o_ws1t), 768, 1536);
  k_packT<<<dim3(48, 24, 1), 256, 0, stream>>>(ws2, (bf16*)(W + o_ws2t), 1536, 768);
  k_packGT<<<dim3(72), 256, 0, stream>>>(gate_a, task, gta, NEA);
  k_packGT<<<dim3(24), 256, 0, stream>>>(gate_f, task, gtf, NEF);

  // 2) zero dense scatter buffer + counts + yacc
  (void)hipMemsetAsync(W + o_dense, 0, 12582912, stream);
  (void)hipMemsetAsync(W + o_cnt, 0, 64, stream);
  (void)hipMemsetAsync(W + o_yacc, 0, 12582912, stream);

  // 3) fused LN1 + routing A (writes h1b bf16, topi, topv)
  k_lnrouteA<<<NTOK / 4, 256, 0, stream>>>(x, ln1g, ln1b, gta, h1b, topi, topv);

  // 4) fused all-expert q + kv projection -> bf16 (N=1664, grid 32x13)
  k_gemm<3><<<dim3(32, 13), 256, 0, stream>>>((const short*)h1b, (const short*)(W + o_btq),
                                              nullptr, hallqb, NQKV, 768);

  // 5) attention (MFMA bf16 flash; Q gathered; scatter fused into epilogue)
  k_packKV<<<dim3(2048), 256, 0, stream>>>(hallqb, b_kv, kvbb);
  k_attn_mfma<<<dim3(16, NHEAD, NB), 256, 0, stream>>>(hallqb, topi, topv, kvbb, dense);

  // 6) output projection + residual: x2 = x, then split-K2 atomicAdd
  (void)hipMemcpyAsync(W + o_x2, (const void*)x, 12582912,
                       hipMemcpyDeviceToDevice, stream);
  k_gemm<4><<<dim3(32, 6, 2), 256, 0, stream>>>((const short*)dense,
      (const short*)(W + o_wqot), x2b, nullptr, 768, 1536);

  // 7) fused LN2 + routing F, then grouping (compact 128-row tile table)
  k_lnrouteF<<<NTOK / 4, 256, 0, stream>>>(x2b, ln2g, ln2b, gtf, h2b, efp, wfp, cntp);
  k_off<<<1, 1, 0, stream>>>(cntp, offp, curp, tmeta, ntl);
  k_fill<<<16, 256, 0, stream>>>(efp, wfp, curp, listp, wslp);

  // 8) MoE FFN (grouped, 128x128 BK=32, XCD-swizzled; phase 1 -> yacc atomics)
  k_gemm_moe<0><<<dim3(MAXTILE, 12), 256, 0, stream>>>((const short*)h2b,
      (const short*)(W + o_w1t), (const short*)(W + o_ws1t), b1f, bs1, nullptr,
      offp, cntp, listp, tmeta, ntl, hmid, nullptr);
  k_gemm_moe<1><<<dim3(MAXTILE, 6), 256, 0, stream>>>((const short*)hmid,
      (const short*)(W + o_w2t), (const short*)(W + o_ws2t), nullptr, nullptr, wslp,
      offp, cntp, listp, tmeta, ntl, nullptr, yacc);

  // 9) final combine
  k_final<<<dim3(12288), 256, 0, stream>>>(x2b, b_out, yacc, (float*)d_out);
}

// Round 15
// 524.552 us; speedup vs baseline: 1.0483x; 1.0483x over previous
//
#include <hip/hip_runtime.h>
#include <hip/hip_bf16.h>

// Problem dims
#define NTOK 4096   // B*N
#define DDIM 768
#define NEA  24
#define NHEAD 12
#define HDIM 64
#define NEF  8
#define HSD  1536
#define SEQL 1024
#define NB   4
#define MAXTILE 104   // <= 72 routed row-tiles + 32 shared row-tiles
#define NQKV 1664     // 1536 q cols + 128 kv cols (fused)

using bf16 = __hip_bfloat16;

typedef float v4f __attribute__((ext_vector_type(4)));
typedef short v8s __attribute__((ext_vector_type(8)));
typedef __bf16 v8bf __attribute__((ext_vector_type(8)));

typedef __attribute__((address_space(3))) unsigned lds_u32_t;
typedef const __attribute__((address_space(1))) unsigned glb_u32_t;

__device__ __forceinline__ void gload16(const void* g, void* l) {
  __builtin_amdgcn_global_load_lds((glb_u32_t*)g, (lds_u32_t*)l, 16, 0, 0);
}

__device__ __forceinline__ float gelu_f(float x) {
  return 0.5f * x * (1.0f + erff(x * 0.70710678118654752440f));
}

__device__ __forceinline__ short f2bf_s(float x) {
  bf16 h = __float2bfloat16(x);
  return __builtin_bit_cast(short, h);
}

// bijective XCD swizzle (nwg % 8 == 0): contiguous chunk per XCD -> L2 reuse
__device__ __forceinline__ int xcd_swz(int lin, int nwg) {
  return (lin & 7) * (nwg >> 3) + (lin >> 3);
}

// ---------------- MFMA GEMM core: 128x128 tile, BK=32 ----------------
// 2-buffer pipeline: stage tile s+1 while computing tile s (R5-verified).
__device__ __forceinline__ void gemm_core(const short* gA0, const short* gA1,
                                          const short* gB0, const short* gB1,
                                          short* lA, short* lB, int steps,
                                          v4f (&acc)[4][4])
{
  const int tid = threadIdx.x;
  const int w = tid >> 6, l = tid & 63;
  const int wr = (w >> 1) * 64, wc = (w & 1) * 64;
  const int fr = l & 15, ko = (l >> 4) * 8;
  const int sb = w * 1024;              // wave staging base (shorts)
  gload16(gA0, lA + sb); gload16(gA1, lA + sb + 512);
  gload16(gB0, lB + sb); gload16(gB1, lB + sb + 512);
  gA0 += 32; gA1 += 32; gB0 += 32; gB1 += 32;
  __syncthreads();                      // drains vmcnt(0): tile 0 visible
  int cur = 0;
  for (int s = 0; s < steps; ++s) {
    const int nxt = cur ^ 1;
    if (s + 1 < steps) {                // issue next tile EARLY (overlaps MFMA)
      gload16(gA0, lA + nxt * 4096 + sb);
      gload16(gA1, lA + nxt * 4096 + sb + 512);
      gload16(gB0, lB + nxt * 4096 + sb);
      gload16(gB1, lB + nxt * 4096 + sb + 512);
      gA0 += 32; gA1 += 32; gB0 += 32; gB1 += 32;
    }
    const short* bA = lA + cur * 4096;
    const short* bB = lB + cur * 4096;
    v8s av[4], bv[4];
#pragma unroll
    for (int mi = 0; mi < 4; ++mi)
      av[mi] = *(const v8s*)(bA + (wr + mi * 16 + fr) * 32 + ko);
#pragma unroll
    for (int ni = 0; ni < 4; ++ni)
      bv[ni] = *(const v8s*)(bB + (wc + ni * 16 + fr) * 32 + ko);
#pragma unroll
    for (int mi = 0; mi < 4; ++mi)
#pragma unroll
      for (int ni = 0; ni < 4; ++ni)
        acc[mi][ni] = __builtin_amdgcn_mfma_f32_16x16x32_bf16(
            __builtin_bit_cast(v8bf, av[mi]), __builtin_bit_cast(v8bf, bv[ni]),
            acc[mi][ni], 0, 0, 0);
    __syncthreads();
    cur = nxt;
  }
}

// dense GEMM: EPI 0 = f32, 2 = f32 +addsrc (residual), 3 = bf16 out.
template<int EPI>
__global__ __launch_bounds__(256, 4) void k_gemm(const short* __restrict__ A,
    const short* __restrict__ Bt, float* __restrict__ C, bf16* __restrict__ Cb,
    const float* __restrict__ addsrc, int N, int K)
{
  const int nwg = gridDim.x * gridDim.y;
  const int swz = xcd_swz(blockIdx.x + gridDim.x * blockIdx.y, nwg);
  const int m0 = (swz % gridDim.x) * 128, n0 = (swz / gridDim.x) * 128;
  __shared__ __align__(16) short lA[2 * 128 * 32];
  __shared__ __align__(16) short lB[2 * 128 * 32];
  const int tid = threadIdx.x, w = tid >> 6, l = tid & 63;
  const int ca = w * 128 + l, cb = ca + 64;
  const short* gA0 = A + (size_t)(m0 + (ca >> 2)) * K + (ca & 3) * 8;
  const short* gA1 = A + (size_t)(m0 + (cb >> 2)) * K + (cb & 3) * 8;
  const short* gB0 = Bt + (size_t)(n0 + (ca >> 2)) * K + (ca & 3) * 8;
  const short* gB1 = Bt + (size_t)(n0 + (cb >> 2)) * K + (cb & 3) * 8;
  v4f acc[4][4];
  v4f z = {0.f, 0.f, 0.f, 0.f};
#pragma unroll
  for (int i = 0; i < 4; ++i)
#pragma unroll
    for (int j = 0; j < 4; ++j) acc[i][j] = z;
  gemm_core(gA0, gA1, gB0, gB1, lA, lB, K >> 5, acc);
  const int wr = (w >> 1) * 64, wc = (w & 1) * 64;
  const int fr = l & 15, rq = (l >> 4) * 4;
#pragma unroll
  for (int mi = 0; mi < 4; ++mi)
#pragma unroll
    for (int ni = 0; ni < 4; ++ni)
#pragma unroll
      for (int j = 0; j < 4; ++j) {
        int rg = m0 + wr + mi * 16 + rq + j;
        int cg = n0 + wc + ni * 16 + fr;
        float v = acc[mi][ni][j];
        if (EPI == 2) v += addsrc[(size_t)rg * N + cg];
        if (EPI == 3) Cb[(size_t)rg * N + cg] = __float2bfloat16(v);
        else          C[(size_t)rg * N + cg] = v;
      }
}

// grouped MoE GEMM over a COMPACT tile table (tmeta[i] = (e<<20)|row0).
// PHASE 0: mid = gelu(h2[token] @ W1 + b1) -> bf16
// PHASE 1: ypart[slot] = w[slot] * (hmid[slot] @ W2) -> f32
// XCD-swizzled grid; 5 blocks/CU (R9-measured optimum).
template<int PHASE>
__global__ __launch_bounds__(256, 5) void k_gemm_moe(
    const short* __restrict__ Aact, const short* __restrict__ Wt,
    const short* __restrict__ Wst, const float* __restrict__ b1f,
    const float* __restrict__ bs1, const float* __restrict__ wsl,
    const int* __restrict__ off, const int* __restrict__ cnt,
    const int* __restrict__ list, const int* __restrict__ tmeta,
    const int* __restrict__ ntl, short* __restrict__ outb,
    float* __restrict__ outf)
{
  constexpr int K = (PHASE == 0) ? DDIM : HSD;
  constexpr int N = (PHASE == 0) ? HSD : DDIM;
  const int nwg = gridDim.x * gridDim.y;
  const int swz = xcd_swz(blockIdx.x + gridDim.x * blockIdx.y, nwg);
  const int ti = swz % gridDim.x;
  const int n0 = (swz / gridDim.x) * 128;
  if (ti >= ntl[0]) return;
  const int mm = tmeta[ti];
  const int e = mm >> 20;
  const int r0 = mm & 0xFFFFF;
  const int base = (e < 8) ? off[e] : NTOK * 2;
  const int c    = (e < 8) ? cnt[e] : NTOK;
  const int rows = c - r0;
  const short* Bt = (e < 8) ? Wt + (size_t)e * N * K : Wst;
  __shared__ __align__(16) short lA[2 * 128 * 32];
  __shared__ __align__(16) short lB[2 * 128 * 32];
  const int tid = threadIdx.x, w = tid >> 6, l = tid & 63;
  const int ca = w * 128 + l, cb = ca + 64;

  auto arowptr = [&](int chunk) -> const short* {
    int r = chunk >> 2;
    int re = (r < rows) ? r : (rows - 1);
    int slot = base + r0 + re;
    if (PHASE == 0) {
      int tok = (e < 8) ? list[slot] : (slot - NTOK * 2);
      return Aact + (size_t)tok * DDIM;
    } else {
      return Aact + (size_t)slot * HSD;
    }
  };
  const short* gA0 = arowptr(ca) + (ca & 3) * 8;
  const short* gA1 = arowptr(cb) + (cb & 3) * 8;
  const short* gB0 = Bt + (size_t)(n0 + (ca >> 2)) * K + (ca & 3) * 8;
  const short* gB1 = Bt + (size_t)(n0 + (cb >> 2)) * K + (cb & 3) * 8;
  v4f acc[4][4];
  v4f z = {0.f, 0.f, 0.f, 0.f};
#pragma unroll
  for (int i = 0; i < 4; ++i)
#pragma unroll
    for (int j = 0; j < 4; ++j) acc[i][j] = z;
  gemm_core(gA0, gA1, gB0, gB1, lA, lB, K >> 5, acc);
  const int wr = (w >> 1) * 64, wc = (w & 1) * 64;
  const int fr = l & 15, rq = (l >> 4) * 4;
  const float* bias = (PHASE == 0) ? ((e < 8) ? b1f + e * HSD : bs1) : nullptr;
#pragma unroll
  for (int mi = 0; mi < 4; ++mi)
#pragma unroll
    for (int ni = 0; ni < 4; ++ni)
#pragma unroll
      for (int j = 0; j < 4; ++j) {
        int rl = wr + mi * 16 + rq + j;
        if (rl >= rows) continue;
        int slot = base + r0 + rl;
        int cg = n0 + wc + ni * 16 + fr;
        float v = acc[mi][ni][j];
        if (PHASE == 0) {
          v = gelu_f(v + bias[cg]);
          outb[(size_t)slot * HSD + cg] = f2bf_s(v);
        } else {
          outf[(size_t)slot * DDIM + cg] = v * wsl[slot];
        }
      }
}

// ------- FUSED LayerNorm + routing A: one wave per token, LN in regs -------
__global__ __launch_bounds__(256) void k_lnrouteA(const float* __restrict__ x,
    const float* __restrict__ lg_, const float* __restrict__ lb_,
    const float* __restrict__ gt, bf16* __restrict__ hb,
    int* __restrict__ topi, float* __restrict__ topv)
{
  const int t = blockIdx.x * 4 + (threadIdx.x >> 6);
  const int l = threadIdx.x & 63;
  const float* xr = x + (size_t)t * DDIM;
  float v[12];
  float s = 0.f, q = 0.f;
#pragma unroll
  for (int m = 0; m < 12; ++m) {
    v[m] = xr[l + 64 * m];
    s += v[m]; q += v[m] * v[m];
  }
#pragma unroll
  for (int m = 32; m >= 1; m >>= 1) { s += __shfl_xor(s, m); q += __shfl_xor(q, m); }
  const float mean = s * (1.f / DDIM);
  const float inv = rsqrtf(q * (1.f / DDIM) - mean * mean + 1e-5f);
  float hr[12];
#pragma unroll
  for (int m = 0; m < 12; ++m) {
    int d = l + 64 * m;
    hr[m] = (v[m] - mean) * inv * lg_[d] + lb_[d];
    hb[(size_t)t * DDIM + d] = __float2bfloat16(hr[m]);
  }
  float lg[NEA];
#pragma unroll
  for (int e = 0; e < NEA; ++e) {
    const float* ge = gt + e * DDIM;
    float a = 0.f;
#pragma unroll
    for (int m = 0; m < 12; ++m) a += hr[m] * ge[l + 64 * m];
#pragma unroll
    for (int m = 32; m >= 1; m >>= 1) a += __shfl_xor(a, m);
    lg[e] = a;
  }
  unsigned used = 0;
  int sel[NHEAD]; float bvk[NHEAD];
#pragma unroll
  for (int k = 0; k < NHEAD; ++k) {
    float bv = -3e30f; int best = 0;
#pragma unroll
    for (int e = 0; e < NEA; ++e)
      if (!((used >> e) & 1u) && lg[e] > bv) { bv = lg[e]; best = e; }
    used |= 1u << best; sel[k] = best; bvk[k] = bv;
  }
  const float mx = bvk[0];
  float pvk[NHEAD], ssum = 0.f;
#pragma unroll
  for (int k = 0; k < NHEAD; ++k) { pvk[k] = expf(bvk[k] - mx); ssum += pvk[k]; }
  const float invs = 1.f / ssum;
  if (l == 0) {
#pragma unroll
    for (int k = 0; k < NHEAD; ++k) {
      topi[t * NHEAD + k] = sel[k];
      topv[t * NHEAD + k] = pvk[k] * invs;
    }
  }
}

// ------- FUSED LayerNorm + routing F -------
__global__ __launch_bounds__(256) void k_lnrouteF(const float* __restrict__ x,
    const float* __restrict__ lg_, const float* __restrict__ lb_,
    const float* __restrict__ gt, bf16* __restrict__ hb,
    int* __restrict__ ef, float* __restrict__ wf, int* __restrict__ cnt)
{
  const int t = blockIdx.x * 4 + (threadIdx.x >> 6);
  const int l = threadIdx.x & 63;
  const float* xr = x + (size_t)t * DDIM;
  float v[12];
  float s = 0.f, q = 0.f;
#pragma unroll
  for (int m = 0; m < 12; ++m) {
    v[m] = xr[l + 64 * m];
    s += v[m]; q += v[m] * v[m];
  }
#pragma unroll
  for (int m = 32; m >= 1; m >>= 1) { s += __shfl_xor(s, m); q += __shfl_xor(q, m); }
  const float mean = s * (1.f / DDIM);
  const float inv = rsqrtf(q * (1.f / DDIM) - mean * mean + 1e-5f);
  float hr[12];
#pragma unroll
  for (int m = 0; m < 12; ++m) {
    int d = l + 64 * m;
    hr[m] = (v[m] - mean) * inv * lg_[d] + lb_[d];
    hb[(size_t)t * DDIM + d] = __float2bfloat16(hr[m]);
  }
  float lg[NEF];
#pragma unroll
  for (int e = 0; e < NEF; ++e) {
    const float* ge = gt + e * DDIM;
    float a = 0.f;
#pragma unroll
    for (int m = 0; m < 12; ++m) a += hr[m] * ge[l + 64 * m];
#pragma unroll
    for (int m = 32; m >= 1; m >>= 1) a += __shfl_xor(a, m);
    lg[e] = a;
  }
  unsigned used = 0;
  int sel[2]; float bvk[2];
#pragma unroll
  for (int k = 0; k < 2; ++k) {
    float bv = -3e30f; int best = 0;
#pragma unroll
    for (int e = 0; e < NEF; ++e)
      if (!((used >> e) & 1u) && lg[e] > bv) { bv = lg[e]; best = e; }
    used |= 1u << best; sel[k] = best; bvk[k] = bv;
  }
  const float mx = bvk[0];
  float p0 = expf(bvk[0] - mx), p1 = expf(bvk[1] - mx);
  const float invs = 1.f / (p0 + p1);
  if (l == 0) {
    ef[t * 2 + 0] = sel[0]; wf[t * 2 + 0] = p0 * invs;
    ef[t * 2 + 1] = sel[1]; wf[t * 2 + 1] = p1 * invs;
    atomicAdd(&cnt[sel[0]], 1);
    atomicAdd(&cnt[sel[1]], 1);
  }
}

// gate transpose for current task: dst[e][d] = src[task][d][e]
__global__ void k_packGT(const float* __restrict__ src, const int* __restrict__ task,
                         float* __restrict__ dst, int E)
{
  int idx = blockIdx.x * 256 + threadIdx.x;
  if (idx >= E * DDIM) return;
  int e = idx / DDIM, d = idx - e * DDIM;
  dst[idx] = src[(size_t)task[0] * DDIM * E + (size_t)d * E + e];
}

// offsets + COMPACT 128-row tile table: tmeta[i] = (expert<<20)|row0
__global__ void k_off(const int* __restrict__ cnt, int* __restrict__ off,
                      int* __restrict__ cur, int* __restrict__ tmeta,
                      int* __restrict__ ntl)
{
  if (threadIdx.x == 0 && blockIdx.x == 0) {
    int a = 0;
    for (int e = 0; e < NEF; ++e) { off[e] = a; cur[e] = a; a += cnt[e]; }
    off[NEF] = a;
    int n = 0;
    for (int e = 0; e < NEF; ++e)
      for (int r = 0; r < cnt[e]; r += 128) tmeta[n++] = (e << 20) | r;
    for (int r = 0; r < NTOK; r += 128) tmeta[n++] = (8 << 20) | r;
    ntl[0] = n;
  }
}

__global__ void k_fill(const int* __restrict__ ef, const float* __restrict__ wf,
                       int* __restrict__ cur, int* __restrict__ list,
                       float* __restrict__ wsl, int* __restrict__ sof)
{
  int t = blockIdx.x * 256 + threadIdx.x;
  if (t >= NTOK) return;
  for (int k = 0; k < 2; ++k) {
    int e = ef[t * 2 + k];
    int slot = atomicAdd(&cur[e], 1);
    list[slot] = t;
    wsl[slot] = wf[t * 2 + k];
    sof[t * 2 + k] = slot;
  }
  list[NTOK * 2 + t] = t;
  wsl[NTOK * 2 + t] = 1.f;
}

// ---------------- attention helpers ----------------
// kv = hallqb cols 1536..1663 (+ b_kv bias) -> bf16 [4096][128]
__global__ void k_packKV(const bf16* __restrict__ hq, const float* __restrict__ bkv,
                         bf16* __restrict__ kvb)
{
  int idx = blockIdx.x * 256 + threadIdx.x;   // < 4096*128
  int t = idx >> 7, j = idx & 127;
  float v = __bfloat162float(hq[(size_t)t * NQKV + 1536 + j]) + bkv[j];
  kvb[idx] = __float2bfloat16(v);
}

// MFMA flash attention + FUSED weighted scatter into dense (bf16).
// grid (N/64, H, B), block 256 (4 waves). Q gathered from hallqb via topi.
__global__ __launch_bounds__(256, 2) void k_attn_mfma(const bf16* __restrict__ hq,
    const int* __restrict__ topi, const float* __restrict__ topv,
    const bf16* __restrict__ kv, bf16* __restrict__ dense)
{
  __shared__ __align__(16) short Qs[64 * 64];
  __shared__ __align__(16) short Ks[64 * 64];
  __shared__ __align__(16) short Vs[64 * 64];   // transposed: row=d, col=j
  __shared__ __align__(16) short Ps[64 * 64];
  const int i0 = blockIdx.x * 64;
  const int h = blockIdx.y;
  const int b = blockIdx.z;
  const int tid = threadIdx.x;
  const int w = tid >> 6, l = tid & 63;
  const int g = l >> 4, fq = l & 15;
  const short* qg = (const short*)hq;
  const short* kvg = (const short*)kv;

  // stage Q (gathered): chunks tid (rows 0..31) and tid+256 (rows 32..63)
  {
    int c0 = tid, c1 = tid + 256;
    int r0 = c0 >> 3, s0 = (c0 & 7) ^ (r0 & 7);
    int r1 = c1 >> 3, s1 = (c1 & 7) ^ (r1 & 7);
    int t0 = b * SEQL + i0 + r0, t1 = b * SEQL + i0 + r1;
    int e0 = topi[t0 * NHEAD + h], e1 = topi[t1 * NHEAD + h];
    gload16(qg + (size_t)t0 * NQKV + e0 * HDIM + s0 * 8, Qs + w * 512);
    gload16(qg + (size_t)t1 * NQKV + e1 * HDIM + s1 * 8, Qs + 2048 + w * 512);
  }

  float m_run[4], l_run[4];
  v4f oacc[4];
#pragma unroll
  for (int r = 0; r < 4; ++r) { m_run[r] = -1e30f; l_run[r] = 0.f; }
#pragma unroll
  for (int nd = 0; nd < 4; ++nd) oacc[nd] = (v4f){0.f, 0.f, 0.f, 0.f};

  const int vj = tid & 63;            // V staging: column j, wave covers d block
  const int vd0 = (tid >> 6) * 16;

  for (int jt = 0; jt < 16; ++jt) {
    if (jt) __syncthreads();          // previous tile's readers done
    // stage K
    {
      int c0 = tid, c1 = tid + 256;
      int r0 = c0 >> 3, s0 = (c0 & 7) ^ (r0 & 7);
      int r1 = c1 >> 3, s1 = (c1 & 7) ^ (r1 & 7);
      gload16(kvg + ((size_t)(b * SEQL + jt * 64 + r0)) * 128 + s0 * 8,
              Ks + w * 512);
      gload16(kvg + ((size_t)(b * SEQL + jt * 64 + r1)) * 128 + s1 * 8,
              Ks + 2048 + w * 512);
    }
    // stage V transposed (reg -> swizzled ds_write)
    {
      const short* gv = kvg + ((size_t)(b * SEQL + jt * 64 + vj)) * 128 + 64 + vd0;
      v8s a0 = *(const v8s*)gv;
      v8s a1 = *(const v8s*)(gv + 8);
#pragma unroll
      for (int k2 = 0; k2 < 8; ++k2) {
        int d = vd0 + k2;
        Vs[d * 64 + (((vj >> 3) ^ (d & 7)) << 3) + (vj & 7)] = a0[k2];
      }
#pragma unroll
      for (int k2 = 0; k2 < 8; ++k2) {
        int d = vd0 + 8 + k2;
        Vs[d * 64 + (((vj >> 3) ^ (d & 7)) << 3) + (vj & 7)] = a1[k2];
      }
    }
    __syncthreads();                  // staged data visible (incl. Q on jt=0)

    // QK^T: S[64q x 64j], this wave: q rows 16w..16w+15
    v8s aq[2];
#pragma unroll
    for (int kk = 0; kk < 2; ++kk)
      aq[kk] = *(const v8s*)&Qs[(16 * w + fq) * 64 + (((kk * 4 + g) ^ (fq & 7)) << 3)];
    v4f sacc[4];
#pragma unroll
    for (int n = 0; n < 4; ++n) {
      sacc[n] = (v4f){0.f, 0.f, 0.f, 0.f};
#pragma unroll
      for (int kk = 0; kk < 2; ++kk) {
        v8s bk = *(const v8s*)&Ks[(16 * n + fq) * 64 + (((kk * 4 + g) ^ (fq & 7)) << 3)];
        sacc[n] = __builtin_amdgcn_mfma_f32_16x16x32_bf16(
            __builtin_bit_cast(v8bf, aq[kk]), __builtin_bit_cast(v8bf, bk),
            sacc[n], 0, 0, 0);
      }
    }
#pragma unroll
    for (int n = 0; n < 4; ++n) sacc[n] *= 0.125f;   // HD^-0.5

    // online softmax; C layout: row = 4g+r (in wave strip), col = 16n+fq
#pragma unroll
    for (int r = 0; r < 4; ++r) {
      float mt = fmaxf(fmaxf(sacc[0][r], sacc[1][r]), fmaxf(sacc[2][r], sacc[3][r]));
      mt = fmaxf(mt, __shfl_xor(mt, 1));
      mt = fmaxf(mt, __shfl_xor(mt, 2));
      mt = fmaxf(mt, __shfl_xor(mt, 4));
      mt = fmaxf(mt, __shfl_xor(mt, 8));
      float mnew = fmaxf(m_run[r], mt);
      float corr = __expf(m_run[r] - mnew);
      float pv[4], ps = 0.f;
#pragma unroll
      for (int n = 0; n < 4; ++n) { pv[n] = __expf(sacc[n][r] - mnew); ps += pv[n]; }
      ps += __shfl_xor(ps, 1);
      ps += __shfl_xor(ps, 2);
      ps += __shfl_xor(ps, 4);
      ps += __shfl_xor(ps, 8);
      l_run[r] = l_run[r] * corr + ps;
      m_run[r] = mnew;
#pragma unroll
      for (int nd = 0; nd < 4; ++nd) oacc[nd][r] *= corr;
      int qrow = 16 * w + 4 * g + r;
#pragma unroll
      for (int n = 0; n < 4; ++n)
        Ps[qrow * 64 + (((2 * n + (fq >> 3)) ^ (qrow & 7)) << 3) + (fq & 7)] =
            f2bf_s(pv[n]);
    }
    // wave-private P: drain LDS writes before cross-lane reads (rule #18)
    asm volatile("s_waitcnt lgkmcnt(0)" ::: "memory");
    __builtin_amdgcn_sched_barrier(0);

    // PV: O[16q x 64d] += P[16q x 64j] @ V[64j x 64d] (Vs holds V^T)
#pragma unroll
    for (int kk = 0; kk < 2; ++kk) {
      v8s pa = *(const v8s*)&Ps[(16 * w + fq) * 64 + (((kk * 4 + g) ^ (fq & 7)) << 3)];
#pragma unroll
      for (int nd = 0; nd < 4; ++nd) {
        v8s vb = *(const v8s*)&Vs[(16 * nd + fq) * 64 + (((kk * 4 + g) ^ (fq & 7)) << 3)];
        oacc[nd] = __builtin_amdgcn_mfma_f32_16x16x32_bf16(
            __builtin_bit_cast(v8bf, pa), __builtin_bit_cast(v8bf, vb),
            oacc[nd], 0, 0, 0);
      }
    }
  }

  // fused epilogue: apply topv weight and scatter into dense (bf16)
#pragma unroll
  for (int r = 0; r < 4; ++r) {
    int t = b * SEQL + i0 + 16 * w + 4 * g + r;
    int e = topi[t * NHEAD + h];
    float sc = topv[t * NHEAD + h] / l_run[r];
#pragma unroll
    for (int nd = 0; nd < 4; ++nd)
      dense[(size_t)t * (NEA * HDIM) + e * HDIM + 16 * nd + fq] =
          __float2bfloat16(oacc[nd][r] * sc);
  }
}

// ---------------- weight packing (tiled transpose, coalesced both sides) ----
__global__ __launch_bounds__(256) void k_packT(const float* __restrict__ src,
                                               bf16* __restrict__ dst, int K, int N)
{
  __shared__ float tile[32][33];
  const size_t zoff = (size_t)blockIdx.z * K * N;
  const int k0 = blockIdx.x * 32, n0 = blockIdx.y * 32;
  const int tx = threadIdx.x & 31, ty = threadIdx.x >> 5;
#pragma unroll
  for (int i = 0; i < 32; i += 8)
    tile[ty + i][tx] = src[zoff + (size_t)(k0 + ty + i) * N + n0 + tx];
  __syncthreads();
#pragma unroll
  for (int i = 0; i < 32; i += 8)
    dst[zoff + (size_t)(n0 + ty + i) * K + k0 + tx] =
        __float2bfloat16(tile[tx][ty + i]);
}

// ---------------- final combine ----------------
__global__ void k_final(const float* __restrict__ x2, const float* __restrict__ bout,
                        const float* __restrict__ yp, const int* __restrict__ sof,
                        float* __restrict__ out)
{
  int idx = blockIdx.x * 256 + threadIdx.x;   // < 4096*768
  int t = idx / DDIM, d = idx - t * DDIM;
  int s0 = sof[2 * t], s1 = sof[2 * t + 1];
  out[idx] = x2[idx] + bout[d] + yp[(size_t)s0 * DDIM + d] + yp[(size_t)s1 * DDIM + d] +
             yp[((size_t)(NTOK * 2) + t) * DDIM + d];
}

extern "C" void kernel_launch(void* const* d_in, const int* in_sizes, int n_in,
                              void* d_out, int out_size, void* d_ws, size_t ws_size,
                              hipStream_t stream) {
  const float* x      = (const float*)d_in[0];
  const int*   task   = (const int*)d_in[1];
  const float* ln1g   = (const float*)d_in[2];
  const float* ln1b   = (const float*)d_in[3];
  const float* ln2g   = (const float*)d_in[4];
  const float* ln2b   = (const float*)d_in[5];
  const float* gate_a = (const float*)d_in[6];
  const float* wq_in  = (const float*)d_in[7];
  const float* wq_out = (const float*)d_in[8];
  const float* w_kv   = (const float*)d_in[9];
  const float* b_kv   = (const float*)d_in[10];
  const float* gate_f = (const float*)d_in[11];
  const float* w1f    = (const float*)d_in[12];
  const float* b1f    = (const float*)d_in[13];
  const float* w2f    = (const float*)d_in[14];
  const float* b_out  = (const float*)d_in[15];
  const float* ws1    = (const float*)d_in[16];
  const float* bs1    = (const float*)d_in[17];
  const float* ws2    = (const float*)d_in[18];

  char* W = (char*)d_ws;
  size_t off_ = 0;
  auto alloc = [&](size_t b) { size_t o = off_; off_ += (b + 255) & ~(size_t)255; return o; };
  // region 1: h1b + hallqb live early; hmid (37.75 MB) reuses the region
  size_t o_reg1  = alloc(37748736);
  size_t o_h1b   = o_reg1;                   // [4096][768] bf16 (6.3 MB)
  size_t o_hallq = o_reg1 + 6291456;         // [4096][1664] bf16 (13.6 MB)
  size_t o_hmid  = o_reg1;                   // [12288][1536] bf16 (37.75 MB)
  // region 2: dense lives early; ypart (37.75 MB) reuses q+o+dense span
  size_t o_q     = alloc(12582912);
  size_t o_o     = alloc(12582912);
  size_t o_dense = alloc(12582912);
  size_t o_ypart = o_q;
  size_t o_kvb   = alloc(1048576);
  size_t o_x2    = alloc(12582912);
  size_t o_h2b   = alloc(6291456);
  size_t o_btq   = alloc(2555904);           // [1664][768] bf16 (Wq_in^T ++ W_kv^T)
  size_t o_wqot  = alloc(2359296);
  size_t o_w1t   = alloc(18874368);
  size_t o_w2t   = alloc(18874368);
  size_t o_ws1t  = alloc(2359296);
  size_t o_ws2t  = alloc(2359296);
  size_t o_topi  = alloc(196608);
  size_t o_topv  = alloc(196608);
  size_t o_ef    = alloc(32768);
  size_t o_wf    = alloc(32768);
  size_t o_cnt   = alloc(1024);
  size_t o_offs  = alloc(1024);
  size_t o_cur   = alloc(1024);
  size_t o_list  = alloc(49152);
  size_t o_wsl   = alloc(49152);
  size_t o_sof   = alloc(32768);
  size_t o_tmeta = alloc(1024);
  size_t o_ntl   = alloc(256);
  size_t o_gta   = alloc(73728);
  size_t o_gtf   = alloc(24576);
  if (ws_size < off_) return;

  bf16*  h1b   = (bf16*)(W + o_h1b);
  bf16*  hallqb= (bf16*)(W + o_hallq);
  bf16*  dense = (bf16*)(W + o_dense);
  bf16*  kvbb  = (bf16*)(W + o_kvb);
  float* x2b   = (float*)(W + o_x2);
  bf16*  h2b   = (bf16*)(W + o_h2b);
  short* hmid  = (short*)(W + o_hmid);
  float* ypart = (float*)(W + o_ypart);
  int*   topi  = (int*)(W + o_topi);
  float* topv  = (float*)(W + o_topv);
  int*   efp   = (int*)(W + o_ef);
  float* wfp   = (float*)(W + o_wf);
  int*   cntp  = (int*)(W + o_cnt);
  int*   offp  = (int*)(W + o_offs);
  int*   curp  = (int*)(W + o_cur);
  int*   listp = (int*)(W + o_list);
  float* wslp  = (float*)(W + o_wsl);
  int*   sofp  = (int*)(W + o_sof);
  int*   tmeta = (int*)(W + o_tmeta);
  int*   ntl   = (int*)(W + o_ntl);
  float* gta   = (float*)(W + o_gta);
  float* gtf   = (float*)(W + o_gtf);

  // 1) pack weights to bf16, transposed (N x K); gates to f32 transposed.
  k_packT<<<dim3(24, 2, 24), 256, 0, stream>>>(wq_in, (bf16*)(W + o_btq), 768, 64);
  k_packT<<<dim3(24, 4, 1), 256, 0, stream>>>(w_kv, (bf16*)(W + o_btq) + 1536 * 768, 768, 128);
  k_packT<<<dim3(48, 24, 1), 256, 0, stream>>>(wq_out, (bf16*)(W + o_wqot), 1536, 768);
  k_packT<<<dim3(24, 48, 8), 256, 0, stream>>>(w1f, (bf16*)(W + o_w1t), 768, 1536);
  k_packT<<<dim3(48, 24, 8), 256, 0, stream>>>(w2f, (bf16*)(W + o_w2t), 1536, 768);
  k_packT<<<dim3(24, 48, 1), 256, 0, stream>>>(ws1, (bf16*)(W + o_ws1t), 768, 1536);
  k_packT<<<dim3(48, 24, 1), 256, 0, stream>>>(ws2, (bf16*)(W + o_ws2t), 1536, 768);
  k_packGT<<<dim3(72), 256, 0, stream>>>(gate_a, task, gta, NEA);
  k_packGT<<<dim3(24), 256, 0, stream>>>(gate_f, task, gtf, NEF);

  // 2) zero dense scatter buffer + counts
  (void)hipMemsetAsync(W + o_dense, 0, 12582912, stream);
  (void)hipMemsetAsync(W + o_cnt, 0, 64, stream);

  // 3) fused LN1 + routing A (writes h1b bf16, topi, topv)
  k_lnrouteA<<<NTOK / 4, 256, 0, stream>>>(x, ln1g, ln1b, gta, h1b, topi, topv);

  // 4) fused all-expert q + kv projection -> bf16 (N=1664, grid 32x13)
  k_gemm<3><<<dim3(32, 13), 256, 0, stream>>>((const short*)h1b, (const short*)(W + o_btq),
                                              nullptr, hallqb, nullptr, NQKV, 768);

  // 5) attention (MFMA bf16 flash; Q gathered; scatter fused into epilogue)
  k_packKV<<<dim3(2048), 256, 0, stream>>>(hallqb, b_kv, kvbb);
  k_attn_mfma<<<dim3(16, NHEAD, NB), 256, 0, stream>>>(hallqb, topi, topv, kvbb, dense);

  // 6) output projection + residual -> x2 (R13-proven EPI 2)
  k_gemm<2><<<dim3(32, 6), 256, 0, stream>>>((const short*)dense, (const short*)(W + o_wqot),
                                             x2b, nullptr, x, 768, 1536);

  // 7) fused LN2 + routing F, then grouping (compact 128-row tile table)
  k_lnrouteF<<<NTOK / 4, 256, 0, stream>>>(x2b, ln2g, ln2b, gtf, h2b, efp, wfp, cntp);
  k_off<<<1, 1, 0, stream>>>(cntp, offp, curp, tmeta, ntl);
  k_fill<<<16, 256, 0, stream>>>(efp, wfp, curp, listp, wslp, sofp);

  // 8) MoE FFN (grouped, 128x128 BK=32, XCD-swizzled, 5 blocks/CU)
  k_gemm_moe<0><<<dim3(MAXTILE, 12), 256, 0, stream>>>((const short*)h2b,
      (const short*)(W + o_w1t), (const short*)(W + o_ws1t), b1f, bs1, nullptr,
      offp, cntp, listp, tmeta, ntl, hmid, nullptr);
  k_gemm_moe<1><<<dim3(MAXTILE, 6), 256, 0, stream>>>((const short*)hmid,
      (const short*)(W + o_w2t), (const short*)(W + o_ws2t), nullptr, nullptr, wslp,
      offp, cntp, listp, tmeta, ntl, nullptr, ypart);

  // 9) final combine
  k_final<<<dim3(12288), 256, 0, stream>>>(x2b, b_out, ypart, sofp, (float*)d_out);
}